// Round 14
// baseline (228.133 us; speedup 1.0000x reference)
//
#include <hip/hip_runtime.h>
#include <math.h>

// Problem constants: B=8, N=2048, DIM=64, H=8
#define BB 8
#define NN 2048
#define DD 64
#define HH 8
#define BH (BB*HH)       // 64
#define HD (HH*DD)       // 512
#define NROWS (BB*NN)    // 16384
#define QKV_COLS (3*HD)  // 1536

typedef __bf16 bf16_8 __attribute__((ext_vector_type(8)));
typedef __bf16 bf16_4 __attribute__((ext_vector_type(4)));
typedef float  f32_16 __attribute__((ext_vector_type(16)));
typedef float  f32_4  __attribute__((ext_vector_type(4)));
typedef int    i32_2  __attribute__((ext_vector_type(2)));

#define QSCALE 0.180336880111f   // 0.125 * log2(e), folded into Q

__device__ __forceinline__ unsigned pack_bf16(float a, float b) {
  union { __bf16 h[2]; unsigned u; } t;
  t.h[0] = (__bf16)a; t.h[1] = (__bf16)b;
  return t.u;
}

__device__ __forceinline__ float fast_exp2(float x) {
#if __has_builtin(__builtin_amdgcn_exp2f)
  return __builtin_amdgcn_exp2f(x);      // raw v_exp_f32
#else
  return __expf(x * 0.69314718056f);
#endif
}

// half-swap across the lane-32 boundary: C-layout row-spread -> A/B-operand
// k-spread (verified rounds 3-13)
__device__ __forceinline__ bf16_8 half_swap(unsigned a0, unsigned a1,
                                            unsigned a2, unsigned a3,
                                            int lhi, int xl) {
  union { unsigned u[4]; bf16_8 v; } F;
#if __has_builtin(__builtin_amdgcn_permlane32_swap)
  i32_2 r02 = __builtin_amdgcn_permlane32_swap((int)a0, (int)a2, false, false);
  i32_2 r13 = __builtin_amdgcn_permlane32_swap((int)a1, (int)a3, false, false);
  F.u[0] = (unsigned)r02.x; F.u[2] = (unsigned)r02.y;
  F.u[1] = (unsigned)r13.x; F.u[3] = (unsigned)r13.y;
#else
  unsigned w0 = (unsigned)__shfl((int)a0, xl, 64);
  unsigned w1 = (unsigned)__shfl((int)a1, xl, 64);
  unsigned w2 = (unsigned)__shfl((int)a2, xl, 64);
  unsigned w3 = (unsigned)__shfl((int)a3, xl, 64);
  F.u[0] = lhi ? w2 : a0;
  F.u[1] = lhi ? w3 : a1;
  F.u[2] = lhi ? a2 : w0;
  F.u[3] = lhi ? a3 : w1;
#endif
  return F.v;
}

// Device-scope grid barrier for a fully co-resident grid (256 blocks).
// cnt/gate zeroed by hipMemsetAsync each call. __syncthreads drains all
// threads' stores to L2; thread-0 __threadfence writes back L2 (release),
// arrives, spins on the gate with device-scope atomics, then __threadfence
// again (invalidate/acquire) before releasing the block.
__device__ __forceinline__ void grid_barrier(unsigned* cnt, unsigned* gate) {
  __syncthreads();
  if (threadIdx.x == 0) {
    __threadfence();
    unsigned old = atomicAdd(cnt, 1u);
    if (old == gridDim.x - 1) {
      atomicExch(gate, 1u);
    } else {
      while (atomicAdd(gate, 0u) == 0u) {
#if __has_builtin(__builtin_amdgcn_s_sleep)
        __builtin_amdgcn_s_sleep(8);
#endif
      }
    }
    __threadfence();
  }
  __syncthreads();
}

// ---------------------------------------------------------------------------
// MEGA-KERNEL: qkv -> [grid barrier] -> attention -> [grid barrier] -> out
// Grid 256 x 512. All phase math is r10-verbatim (best measured config).
// Single launch deletes ~2 inter-kernel gaps + dispatch ramps (~40 µs tail).
// ---------------------------------------------------------------------------
#define TILE_ELEMS (128 * 72 + 64 * 136)   // 17920 bf16 = 35840 B per buffer

__global__ __launch_bounds__(512, 2) void mha_mega(
    const float* __restrict__ x, const float* __restrict__ Wqkv,
    const float* __restrict__ Wout, const float* __restrict__ bout,
    __bf16* __restrict__ Q, __bf16* __restrict__ K, __bf16* __restrict__ Vt,
    __bf16* __restrict__ z, __bf16* __restrict__ Wob,
    float* __restrict__ out, unsigned* __restrict__ bar) {
  __shared__ __align__(16) unsigned char SMEMRAW[2 * TILE_ELEMS * 2];  // 71680 B

  const int tid  = threadIdx.x;
  const int wave = tid >> 6;
  const int lane = tid & 63;
  const int l31  = lane & 31;
  const int lhi  = lane >> 5;
  const int xl   = lane ^ 32;

  // ======================= Phase 1: Wob prep + QKV =========================
  {
    int gid = blockIdx.x * 512 + tid;
    if (gid < 512 * 64) {               // Wout [512][64] -> Wob B-frag layout
      int kf = gid >> 6, col = gid & 63;
      int s = kf >> 4, lh = (kf >> 3) & 1, j = kf & 7;
      int t = col >> 5, lc = col & 31;
      Wob[((size_t)((t * 32 + s) * 64 + lh * 32 + lc)) * 8 + j] = (__bf16)Wout[gid];
    }

    __bf16* Tq = (__bf16*)SMEMRAW + wave * (64 * 34);   // per-wave tile
    const int gwave = blockIdx.x * 8 + wave;            // 0..2047

#pragma unroll 1
    for (int t = 0; t < 6; t++) {
      const int task = t * 2048 + gwave;   // 0..12287 = 24 cg x 512 row-tiles
      const int cg   = task >> 9;
      const int row0 = (task & 511) * 32;

      // A-frags: A[m=l31][k = s*16 + lhi*8 + j], fp32 -> bf16
      const float* xr = x + (size_t)(row0 + l31) * 64 + lhi * 8;
      bf16_8 af[4];
#pragma unroll
      for (int s = 0; s < 4; s++) {
        f32_4 a0 = *(const f32_4*)(xr + s * 16);
        f32_4 a1 = *(const f32_4*)(xr + s * 16 + 4);
#pragma unroll
        for (int j = 0; j < 4; j++) { af[s][j] = (__bf16)a0[j]; af[s][4 + j] = (__bf16)a1[j]; }
      }

      const int col0  = cg * 64;
      const int which = col0 >> 9;        // 0=Q 1=K 2=V
      const float wscl = (which == 0) ? QSCALE : 1.0f;

      f32_16 C0, C1;
#pragma unroll
      for (int q = 0; q < 16; q++) { C0[q] = 0.f; C1[q] = 0.f; }

#pragma unroll
      for (int s = 0; s < 4; s++) {
        bf16_8 b0, b1;
#pragma unroll
        for (int j = 0; j < 8; j++) {
          int k = s * 16 + lhi * 8 + j;
          b0[j] = (__bf16)(Wqkv[(size_t)k * QKV_COLS + col0 + l31]      * wscl);
          b1[j] = (__bf16)(Wqkv[(size_t)k * QKV_COLS + col0 + 32 + l31] * wscl);
        }
        C0 = __builtin_amdgcn_mfma_f32_32x32x16_bf16(af[s], b0, C0, 0, 0, 0);
        C1 = __builtin_amdgcn_mfma_f32_32x32x16_bf16(af[s], b1, C1, 0, 0, 0);
      }

      const int h   = (col0 >> 6) & 7;
      const int bb  = row0 >> 11;
      const int n0l = row0 & 2047;

      if (which < 2) {
        __bf16* dst = (which == 0) ? Q : K;
#pragma unroll
        for (int r = 0; r < 16; r++) {
          int nl = (r & 3) + 8 * (r >> 2) + 4 * lhi;
          size_t base = (((size_t)(bb * HH + h) * NN) + n0l + nl) * DD;
          dst[base + l31]      = (__bf16)C0[r];
          dst[base + 32 + l31] = (__bf16)C1[r];
        }
      } else {
        // transpose 32n x 64d -> Vt[bh][d][n] (wave-private tile, in-order)
#pragma unroll
        for (int r = 0; r < 16; r++) {
          int nl = (r & 3) + 8 * (r >> 2) + 4 * lhi;
          Tq[l31 * 34 + nl]        = (__bf16)C0[r];
          Tq[(32 + l31) * 34 + nl] = (__bf16)C1[r];
        }
        __bf16* dst = Vt + (((size_t)(bb * HH + h) * DD) + lane) * NN + n0l;
#pragma unroll
        for (int j = 0; j < 4; j++) {
          *(bf16_8*)(dst + j * 8) = *(const bf16_8*)(&Tq[lane * 34 + j * 8]);
        }
      }
    }
  }

  grid_barrier(&bar[0], &bar[1]);

  // ======================= Phase 2: attention (r10) ========================
  {
    __bf16 (*SMEM)[TILE_ELEMS] = (__bf16 (*)[TILE_ELEMS])SMEMRAW;
    const int bh = blockIdx.x >> 2;                     // 0..63
    const int q0 = (blockIdx.x & 3) * 512 + wave * 64;  // 64 queries/wave

    const __bf16* Qbase = Q + ((size_t)bh * NN + q0 + l31) * DD + lhi * 8;
    bf16_8 qfa[4], qfb[4];
#pragma unroll
    for (int s = 0; s < 4; s++) {
      qfa[s] = *(const bf16_8*)(Qbase + s * 16);
      qfb[s] = *(const bf16_8*)(Qbase + (size_t)32 * DD + s * 16);
    }

    f32_16 O0a, O1a, O0b, O1b;
#pragma unroll
    for (int i = 0; i < 16; i++) { O0a[i] = 0.f; O1a[i] = 0.f; O0b[i] = 0.f; O1b[i] = 0.f; }
    float lsa = 0.f, lsb = 0.f;

    const __bf16* Kb = K  + (size_t)bh * NN * DD;
    const __bf16* Vb = Vt + (size_t)bh * DD * NN;

    const int krow = tid >> 3, kcol = (tid & 7) * 8;    // K: 128 x 64
    const int vrow = tid >> 4, vcol = (tid & 15) * 8;   // V: 64 x 128
    const __bf16* kgl = Kb + (size_t)krow * 64 + kcol;
    const __bf16* vgl = Vb + (size_t)vrow * NN + vcol;
    const int koff0 = krow * 72 + kcol;
    const int voff0 = 128 * 72 + vrow * 136 + vcol;

    bf16_8 gk[2], gv[2];
#pragma unroll
    for (int i = 0; i < 2; i++) {
      gk[i] = *(const bf16_8*)(kgl + (size_t)i * 64 * 64);
      gv[i] = *(const bf16_8*)(vgl + (size_t)i * 32 * NN);
    }
    {
      __bf16* S = SMEM[0];
      *(bf16_8*)(S + koff0)            = gk[0];
      *(bf16_8*)(S + koff0 + 64 * 72)  = gk[1];
      *(bf16_8*)(S + voff0)            = gv[0];
      *(bf16_8*)(S + voff0 + 32 * 136) = gv[1];
    }
#pragma unroll
    for (int i = 0; i < 2; i++) {
      gk[i] = *(const bf16_8*)(kgl + (size_t)128 * 64 + (size_t)i * 64 * 64);
      gv[i] = *(const bf16_8*)(vgl + 128 + (size_t)i * 32 * NN);
    }
    __syncthreads();

    for (int it = 0; it < 16; it++) {
      __bf16* Ks = SMEM[it & 1];
      __bf16* Vs = SMEM[it & 1] + 128 * 72;

      if (it < 15) {
        __bf16* Sn = SMEM[(it + 1) & 1];
        *(bf16_8*)(Sn + koff0)            = gk[0];
        *(bf16_8*)(Sn + koff0 + 64 * 72)  = gk[1];
        *(bf16_8*)(Sn + voff0)            = gv[0];
        *(bf16_8*)(Sn + voff0 + 32 * 136) = gv[1];
        if (it < 14) {
          const size_t kadv = (size_t)(it + 2) * 128 * 64;
          const size_t vadv = (size_t)(it + 2) * 128;
#pragma unroll
          for (int i = 0; i < 2; i++) {
            gk[i] = *(const bf16_8*)(kgl + kadv + (size_t)i * 64 * 64);
            gv[i] = *(const bf16_8*)(vgl + vadv + (size_t)i * 32 * NN);
          }
        }
      }

#pragma unroll
      for (int grp = 0; grp < 4; grp++) {
        const int kb0 = grp * 32;

        f32_16 Sa, Sb;
#pragma unroll
        for (int i = 0; i < 16; i++) { Sa[i] = 0.f; Sb[i] = 0.f; }
#pragma unroll
        for (int s = 0; s < 4; s++) {
          bf16_8 kb = *(const bf16_8*)(&Ks[(kb0 + l31) * 72 + s * 16 + lhi * 8]);
          Sa = __builtin_amdgcn_mfma_f32_32x32x16_bf16(kb, qfa[s], Sa, 0, 0, 0);
          Sb = __builtin_amdgcn_mfma_f32_32x32x16_bf16(kb, qfb[s], Sb, 0, 0, 0);
        }

        unsigned pka[8], pkb[8];
#pragma unroll
        for (int t = 0; t < 8; t++) {
          float a0 = fast_exp2(Sa[2 * t]), a1 = fast_exp2(Sa[2 * t + 1]);
          lsa += a0 + a1;
          pka[t] = pack_bf16(a0, a1);
          float b0 = fast_exp2(Sb[2 * t]), b1 = fast_exp2(Sb[2 * t + 1]);
          lsb += b0 + b1;
          pkb[t] = pack_bf16(b0, b1);
        }

#pragma unroll
        for (int g = 0; g < 2; g++) {
          const int kc = kb0 + g * 16;
          bf16_8 va0 = *(const bf16_8*)(&Vs[l31 * 136 + kc + lhi * 8]);
          bf16_8 va1 = *(const bf16_8*)(&Vs[(32 + l31) * 136 + kc + lhi * 8]);
          bf16_8 Fa = half_swap(pka[g * 4], pka[g * 4 + 1], pka[g * 4 + 2], pka[g * 4 + 3], lhi, xl);
          O0a = __builtin_amdgcn_mfma_f32_32x32x16_bf16(va0, Fa, O0a, 0, 0, 0);
          O1a = __builtin_amdgcn_mfma_f32_32x32x16_bf16(va1, Fa, O1a, 0, 0, 0);
          bf16_8 Fb = half_swap(pkb[g * 4], pkb[g * 4 + 1], pkb[g * 4 + 2], pkb[g * 4 + 3], lhi, xl);
          O0b = __builtin_amdgcn_mfma_f32_32x32x16_bf16(va0, Fb, O0b, 0, 0, 0);
          O1b = __builtin_amdgcn_mfma_f32_32x32x16_bf16(va1, Fb, O1b, 0, 0, 0);
        }
      }
      __syncthreads();
    }

    lsa += __shfl_xor(lsa, 32, 64);
    lsb += __shfl_xor(lsb, 32, 64);
    const float inva = 1.f / lsa;
    const float invb = 1.f / lsb;

    const int bb = bh >> 3, h = bh & 7;
    __bf16* ow = SMEM[0] + wave * (32 * 68);
    const int qr = lane >> 1, c0 = (lane & 1) * 32;
#pragma unroll
    for (int sub = 0; sub < 2; sub++) {
      const f32_16& P0 = sub ? O0b : O0a;
      const f32_16& P1 = sub ? O1b : O1a;
      const float inv = sub ? invb : inva;
#pragma unroll
      for (int g = 0; g < 4; g++) {
        bf16_4 p0, p1;
#pragma unroll
        for (int i = 0; i < 4; i++) {
          p0[i] = (__bf16)(P0[4 * g + i] * inv);
          p1[i] = (__bf16)(P1[4 * g + i] * inv);
        }
        const int d0 = 8 * g + 4 * lhi;
        *(bf16_4*)(ow + l31 * 68 + d0)      = p0;
        *(bf16_4*)(ow + l31 * 68 + 32 + d0) = p1;
      }
      __bf16* zp = z + ((size_t)bb * NN + q0 + sub * 32 + qr) * HD + h * DD + c0;
#pragma unroll
      for (int j = 0; j < 4; j++) {
        *(bf16_8*)(zp + 8 * j) = *(const bf16_8*)(ow + qr * 68 + c0 + 8 * j);
      }
    }
  }

  grid_barrier(&bar[2], &bar[3]);

  // ======================= Phase 3: out projection =========================
  {
    const int sb = wave >> 2, w4 = wave & 3;            // 2 sub-blocks x 4 waves
    const int row0 = (blockIdx.x * 2 + sb) * 32;
    float (*red)[64][33] = (float (*)[64][33])(SMEMRAW + sb * 25344);

    const __bf16* zr = z + (size_t)(row0 + l31) * HD + w4 * 128 + lhi * 8;

    f32_16 C0, C1;
#pragma unroll
    for (int i = 0; i < 16; i++) { C0[i] = 0.f; C1[i] = 0.f; }

#pragma unroll
    for (int s = 0; s < 8; s++) {
      const int sa = w4 * 8 + s;
      bf16_8 a  = *(const bf16_8*)(zr + s * 16);
      bf16_8 b0 = *(const bf16_8*)(Wob + ((size_t)((0 * 32 + sa) * 64 + lane)) * 8);
      bf16_8 b1 = *(const bf16_8*)(Wob + ((size_t)((1 * 32 + sa) * 64 + lane)) * 8);
      C0 = __builtin_amdgcn_mfma_f32_32x32x16_bf16(a, b0, C0, 0, 0, 0);
      C1 = __builtin_amdgcn_mfma_f32_32x32x16_bf16(a, b1, C1, 0, 0, 0);
    }

    if (w4) {
      float* rw = &red[w4 - 1][lane][0];
#pragma unroll
      for (int r = 0; r < 16; r++) { rw[r] = C0[r]; rw[16 + r] = C1[r]; }
    }
    __syncthreads();
    if (w4 == 0) {
      const float bi0 = bout[l31], bi1 = bout[32 + l31];
#pragma unroll
      for (int r = 0; r < 16; r++) {
        int n = row0 + (r & 3) + 8 * (r >> 2) + 4 * lhi;
        float v0 = C0[r] + red[0][lane][r]      + red[1][lane][r]      + red[2][lane][r];
        float v1 = C1[r] + red[0][lane][16 + r] + red[1][lane][16 + r] + red[2][lane][16 + r];
        out[(size_t)n * 64 + l31]      = v0 + bi0;
        out[(size_t)n * 64 + 32 + l31] = v1 + bi1;
      }
    }
  }
}

// ---------------------------------------------------------------------------
extern "C" void kernel_launch(void* const* d_in, const int* in_sizes, int n_in,
                              void* d_out, int out_size, void* d_ws, size_t ws_size,
                              hipStream_t stream) {
  const float* x    = (const float*)d_in[0];
  const float* Wqkv = (const float*)d_in[1];
  const float* Wout = (const float*)d_in[2];
  const float* bout = (const float*)d_in[3];
  float* out = (float*)d_out;

  const size_t buf_elems = (size_t)BB * HH * NN * DD;  // 8388608
  __bf16* Qw  = (__bf16*)d_ws;
  __bf16* Kw  = Qw  + buf_elems;
  __bf16* Vtw = Kw  + buf_elems;
  __bf16* zw  = Vtw + buf_elems;
  __bf16* Wob = zw  + buf_elems;                        // 32768 bf16
  unsigned* bar = (unsigned*)(Wob + 32768);             // 4 words (aligned)

  hipMemsetAsync(bar, 0, 64, stream);                   // zero barrier state
  mha_mega<<<256, 512, 0, stream>>>(x, Wqkv, Wout, bout,
                                    Qw, Kw, Vtw, zw, Wob, out, bar);
}

// Round 15
// 168.754 us; speedup vs baseline: 1.3519x; 1.3519x over previous
//
#include <hip/hip_runtime.h>
#include <math.h>

// Problem constants: B=8, N=2048, DIM=64, H=8
#define BB 8
#define NN 2048
#define DD 64
#define HH 8
#define BH (BB*HH)       // 64
#define HD (HH*DD)       // 512
#define NROWS (BB*NN)    // 16384
#define QKV_COLS (3*HD)  // 1536

typedef __bf16 bf16_8 __attribute__((ext_vector_type(8)));
typedef __bf16 bf16_4 __attribute__((ext_vector_type(4)));
typedef float  f32_16 __attribute__((ext_vector_type(16)));
typedef float  f32_4  __attribute__((ext_vector_type(4)));
typedef int    i32_2  __attribute__((ext_vector_type(2)));

#define QSCALE 0.180336880111f   // 0.125 * log2(e), folded into Q

__device__ __forceinline__ unsigned pack_bf16(float a, float b) {
  union { __bf16 h[2]; unsigned u; } t;
  t.h[0] = (__bf16)a; t.h[1] = (__bf16)b;
  return t.u;
}

__device__ __forceinline__ float fast_exp2(float x) {
#if __has_builtin(__builtin_amdgcn_exp2f)
  return __builtin_amdgcn_exp2f(x);      // raw v_exp_f32
#else
  return __expf(x * 0.69314718056f);
#endif
}

// half-swap across the lane-32 boundary: C-layout row-spread -> A/B-operand
// k-spread (verified rounds 3-14)
__device__ __forceinline__ bf16_8 half_swap(unsigned a0, unsigned a1,
                                            unsigned a2, unsigned a3,
                                            int lhi, int xl) {
  union { unsigned u[4]; bf16_8 v; } F;
#if __has_builtin(__builtin_amdgcn_permlane32_swap)
  i32_2 r02 = __builtin_amdgcn_permlane32_swap((int)a0, (int)a2, false, false);
  i32_2 r13 = __builtin_amdgcn_permlane32_swap((int)a1, (int)a3, false, false);
  F.u[0] = (unsigned)r02.x; F.u[2] = (unsigned)r02.y;
  F.u[1] = (unsigned)r13.x; F.u[3] = (unsigned)r13.y;
#else
  unsigned w0 = (unsigned)__shfl((int)a0, xl, 64);
  unsigned w1 = (unsigned)__shfl((int)a1, xl, 64);
  unsigned w2 = (unsigned)__shfl((int)a2, xl, 64);
  unsigned w3 = (unsigned)__shfl((int)a3, xl, 64);
  F.u[0] = lhi ? w2 : a0;
  F.u[1] = lhi ? w3 : a1;
  F.u[2] = lhi ? a2 : w0;
  F.u[3] = lhi ? a3 : w1;
#endif
  return F.v;
}

// ---------------------------------------------------------------------------
// Kernel 1: QKV projection via MFMA, W panel staged ONCE per block in LDS as
// scale-folded bf16 (kills r10's 256 scalar global W-loads + ~1200 VALU per
// wave). Block = 8 waves = 256 rows x one 64-col group; grid (24, 64) + one
// prep row (blockIdx.y==64) that builds Wob for out_proj (read only by the
// later kernel -> no intra-kernel ordering hazard).
// LDS: Wl bf16 [64 cols][68] (8704 B, 2-way worst alias = free) +
//      per-wave V-transpose tiles 8 x [64][34] (34816 B) = 43.5 KB.
// ---------------------------------------------------------------------------
__global__ __launch_bounds__(512) void qkv_kernel(
    const float* __restrict__ x, const float* __restrict__ Wqkv,
    const float* __restrict__ Wout,
    __bf16* __restrict__ Q, __bf16* __restrict__ K, __bf16* __restrict__ Vt,
    __bf16* __restrict__ Wob) {
  __shared__ __bf16 Wl[64 * 68];        // [col][k], pitch 68
  __shared__ __bf16 T[8][64][34];       // per-wave V-transpose tiles

  const int tid = threadIdx.x;

  if (blockIdx.y == 64) {               // Wob prep row (24 blocks x 512 thr)
    for (int e = blockIdx.x * 512 + tid; e < 512 * 64; e += 24 * 512) {
      int kf = e >> 6, col = e & 63;
      int s = kf >> 4, lh = (kf >> 3) & 1, j = kf & 7;
      int t = col >> 5, lc = col & 31;
      Wob[((size_t)((t * 32 + s) * 64 + lh * 32 + lc)) * 8 + j] = (__bf16)Wout[e];
    }
    return;
  }

  const int wave = tid >> 6;
  const int lane = tid & 63;
  const int l31  = lane & 31, lhi = lane >> 5;
  const int cg    = blockIdx.x;         // 0..23 (64-col group)
  const int col0  = cg * 64;
  const int which = col0 >> 9;          // 0=Q 1=K 2=V
  const float wscl = (which == 0) ? QSCALE : 1.0f;

  // ---- stage W panel: thread t covers col=t&63, k in [8*(t>>6), +8) ----
  {
    const int c  = tid & 63;
    const int k0 = (tid >> 6) * 8;
    bf16_8 w;
#pragma unroll
    for (int j = 0; j < 8; j++) {
      w[j] = (__bf16)(Wqkv[(size_t)(k0 + j) * QKV_COLS + col0 + c] * wscl);
    }
    *(bf16_8*)(&Wl[c * 68 + k0]) = w;   // coalesced-enough, once per block
  }
  __syncthreads();

  const int row0 = blockIdx.y * 256 + wave * 32;
  const int b    = row0 >> 11;
  const int n0l  = row0 & 2047;

  // A-frags: A[m=l31][k = s*16 + lhi*8 + j], fp32 -> bf16
  const float* xr = x + (size_t)(row0 + l31) * 64 + lhi * 8;
  bf16_8 af[4];
#pragma unroll
  for (int s = 0; s < 4; s++) {
    f32_4 a0 = *(const f32_4*)(xr + s * 16);
    f32_4 a1 = *(const f32_4*)(xr + s * 16 + 4);
#pragma unroll
    for (int j = 0; j < 4; j++) { af[s][j] = (__bf16)a0[j]; af[s][4 + j] = (__bf16)a1[j]; }
  }

  f32_16 C0, C1;
#pragma unroll
  for (int i = 0; i < 16; i++) { C0[i] = 0.f; C1[i] = 0.f; }

  // B-frags: 8 ds_read_b128 per wave (lane n=col, k along register)
#pragma unroll
  for (int s = 0; s < 4; s++) {
    bf16_8 b0 = *(const bf16_8*)(&Wl[l31 * 68 + s * 16 + lhi * 8]);
    bf16_8 b1 = *(const bf16_8*)(&Wl[(32 + l31) * 68 + s * 16 + lhi * 8]);
    C0 = __builtin_amdgcn_mfma_f32_32x32x16_bf16(af[s], b0, C0, 0, 0, 0);
    C1 = __builtin_amdgcn_mfma_f32_32x32x16_bf16(af[s], b1, C1, 0, 0, 0);
  }

  const int h = cg & 7;

  if (which < 2) {
    __bf16* dst = (which == 0) ? Q : K;
#pragma unroll
    for (int r = 0; r < 16; r++) {
      int nl = (r & 3) + 8 * (r >> 2) + 4 * lhi;
      size_t base = (((size_t)(b * HH + h) * NN) + n0l + nl) * DD;
      dst[base + l31]      = (__bf16)C0[r];
      dst[base + 32 + l31] = (__bf16)C1[r];
    }
  } else {
    // transpose 32n x 64d -> Vt[bh][d][n]  (wave-private tile, no barrier)
    __bf16 (*Tw)[34] = T[wave];
#pragma unroll
    for (int r = 0; r < 16; r++) {
      int nl = (r & 3) + 8 * (r >> 2) + 4 * lhi;
      Tw[l31][nl]      = (__bf16)C0[r];
      Tw[32 + l31][nl] = (__bf16)C1[r];
    }
    __bf16* dst = Vt + (((size_t)(b * HH + h) * DD) + lane) * NN + n0l;
#pragma unroll
    for (int j = 0; j < 4; j++) {
      *(bf16_8*)(dst + j * 8) = *(const bf16_8*)(&Tw[lane][j * 8]);
    }
  }
}

// ---------------------------------------------------------------------------
// Kernel 2: flash attention — r10 VERBATIM (best measured: 85-88 µs).
// ---------------------------------------------------------------------------
#define TILE_ELEMS (128 * 72 + 64 * 136)   // 17920 bf16 = 35840 B per buffer
__global__ __launch_bounds__(512, 2) void attn_kernel(
    const __bf16* __restrict__ Q, const __bf16* __restrict__ K,
    const __bf16* __restrict__ Vt, __bf16* __restrict__ z) {
  __shared__ __bf16 SMEM[2][TILE_ELEMS];   // 71680 B

  const int tid  = threadIdx.x;
  const int wave = tid >> 6;
  const int lane = tid & 63;
  const int l31  = lane & 31;
  const int lhi  = lane >> 5;
  const int xl   = lane ^ 32;
  const int bh   = blockIdx.x >> 2;                     // 0..63
  const int q0   = (blockIdx.x & 3) * 512 + wave * 64;  // 64 queries/wave

  const __bf16* Qbase = Q + ((size_t)bh * NN + q0 + l31) * DD + lhi * 8;
  bf16_8 qfa[4], qfb[4];
#pragma unroll
  for (int s = 0; s < 4; s++) {
    qfa[s] = *(const bf16_8*)(Qbase + s * 16);
    qfb[s] = *(const bf16_8*)(Qbase + (size_t)32 * DD + s * 16);
  }

  f32_16 O0a, O1a, O0b, O1b;
#pragma unroll
  for (int i = 0; i < 16; i++) { O0a[i] = 0.f; O1a[i] = 0.f; O0b[i] = 0.f; O1b[i] = 0.f; }
  float lsa = 0.f, lsb = 0.f;

  const __bf16* Kb = K  + (size_t)bh * NN * DD;
  const __bf16* Vb = Vt + (size_t)bh * DD * NN;

  const int krow = tid >> 3, kcol = (tid & 7) * 8;    // K: 128 x 64
  const int vrow = tid >> 4, vcol = (tid & 15) * 8;   // V: 64 x 128
  const __bf16* kgl = Kb + (size_t)krow * 64 + kcol;
  const __bf16* vgl = Vb + (size_t)vrow * NN + vcol;
  const int koff0 = krow * 72 + kcol;
  const int voff0 = 128 * 72 + vrow * 136 + vcol;

  bf16_8 gk[2], gv[2];
#pragma unroll
  for (int i = 0; i < 2; i++) {
    gk[i] = *(const bf16_8*)(kgl + (size_t)i * 64 * 64);
    gv[i] = *(const bf16_8*)(vgl + (size_t)i * 32 * NN);
  }
  {
    __bf16* S = SMEM[0];
    *(bf16_8*)(S + koff0)            = gk[0];
    *(bf16_8*)(S + koff0 + 64 * 72)  = gk[1];
    *(bf16_8*)(S + voff0)            = gv[0];
    *(bf16_8*)(S + voff0 + 32 * 136) = gv[1];
  }
#pragma unroll
  for (int i = 0; i < 2; i++) {
    gk[i] = *(const bf16_8*)(kgl + (size_t)128 * 64 + (size_t)i * 64 * 64);
    gv[i] = *(const bf16_8*)(vgl + 128 + (size_t)i * 32 * NN);
  }
  __syncthreads();

  for (int it = 0; it < 16; it++) {
    __bf16* Ks = SMEM[it & 1];
    __bf16* Vs = SMEM[it & 1] + 128 * 72;

    if (it < 15) {
      __bf16* Sn = SMEM[(it + 1) & 1];
      *(bf16_8*)(Sn + koff0)            = gk[0];
      *(bf16_8*)(Sn + koff0 + 64 * 72)  = gk[1];
      *(bf16_8*)(Sn + voff0)            = gv[0];
      *(bf16_8*)(Sn + voff0 + 32 * 136) = gv[1];
      if (it < 14) {
        const size_t kadv = (size_t)(it + 2) * 128 * 64;
        const size_t vadv = (size_t)(it + 2) * 128;
#pragma unroll
        for (int i = 0; i < 2; i++) {
          gk[i] = *(const bf16_8*)(kgl + kadv + (size_t)i * 64 * 64);
          gv[i] = *(const bf16_8*)(vgl + vadv + (size_t)i * 32 * NN);
        }
      }
    }

#pragma unroll
    for (int grp = 0; grp < 4; grp++) {
      const int kb0 = grp * 32;

      f32_16 Sa, Sb;
#pragma unroll
      for (int i = 0; i < 16; i++) { Sa[i] = 0.f; Sb[i] = 0.f; }
#pragma unroll
      for (int s = 0; s < 4; s++) {
        bf16_8 kb = *(const bf16_8*)(&Ks[(kb0 + l31) * 72 + s * 16 + lhi * 8]);
        Sa = __builtin_amdgcn_mfma_f32_32x32x16_bf16(kb, qfa[s], Sa, 0, 0, 0);
        Sb = __builtin_amdgcn_mfma_f32_32x32x16_bf16(kb, qfb[s], Sb, 0, 0, 0);
      }

      unsigned pka[8], pkb[8];
#pragma unroll
      for (int t = 0; t < 8; t++) {
        float a0 = fast_exp2(Sa[2 * t]), a1 = fast_exp2(Sa[2 * t + 1]);
        lsa += a0 + a1;
        pka[t] = pack_bf16(a0, a1);
        float b0 = fast_exp2(Sb[2 * t]), b1 = fast_exp2(Sb[2 * t + 1]);
        lsb += b0 + b1;
        pkb[t] = pack_bf16(b0, b1);
      }

#pragma unroll
      for (int g = 0; g < 2; g++) {
        const int kc = kb0 + g * 16;
        bf16_8 va0 = *(const bf16_8*)(&Vs[l31 * 136 + kc + lhi * 8]);
        bf16_8 va1 = *(const bf16_8*)(&Vs[(32 + l31) * 136 + kc + lhi * 8]);
        bf16_8 Fa = half_swap(pka[g * 4], pka[g * 4 + 1], pka[g * 4 + 2], pka[g * 4 + 3], lhi, xl);
        O0a = __builtin_amdgcn_mfma_f32_32x32x16_bf16(va0, Fa, O0a, 0, 0, 0);
        O1a = __builtin_amdgcn_mfma_f32_32x32x16_bf16(va1, Fa, O1a, 0, 0, 0);
        bf16_8 Fb = half_swap(pkb[g * 4], pkb[g * 4 + 1], pkb[g * 4 + 2], pkb[g * 4 + 3], lhi, xl);
        O0b = __builtin_amdgcn_mfma_f32_32x32x16_bf16(va0, Fb, O0b, 0, 0, 0);
        O1b = __builtin_amdgcn_mfma_f32_32x32x16_bf16(va1, Fb, O1b, 0, 0, 0);
      }
    }
    __syncthreads();
  }

  lsa += __shfl_xor(lsa, 32, 64);
  lsb += __shfl_xor(lsb, 32, 64);
  const float inva = 1.f / lsa;
  const float invb = 1.f / lsb;

  const int b = bh >> 3, h = bh & 7;
  __bf16* ow = SMEM[0] + wave * (32 * 68);
  const int qr = lane >> 1, c0 = (lane & 1) * 32;
#pragma unroll
  for (int sub = 0; sub < 2; sub++) {
    const f32_16& P0 = sub ? O0b : O0a;
    const f32_16& P1 = sub ? O1b : O1a;
    const float inv = sub ? invb : inva;
#pragma unroll
    for (int g = 0; g < 4; g++) {
      bf16_4 p0, p1;
#pragma unroll
      for (int i = 0; i < 4; i++) {
        p0[i] = (__bf16)(P0[4 * g + i] * inv);
        p1[i] = (__bf16)(P1[4 * g + i] * inv);
      }
      const int d0 = 8 * g + 4 * lhi;
      *(bf16_4*)(ow + l31 * 68 + d0)      = p0;
      *(bf16_4*)(ow + l31 * 68 + 32 + d0) = p1;
    }
    __bf16* zp = z + ((size_t)b * NN + q0 + sub * 32 + qr) * HD + h * DD + c0;
#pragma unroll
    for (int j = 0; j < 4; j++) {
      *(bf16_8*)(zp + 8 * j) = *(const bf16_8*)(ow + qr * 68 + c0 + 8 * j);
    }
  }
}

// ---------------------------------------------------------------------------
// Kernel 3: out projection, k-split x4 (r10-verbatim).
// ---------------------------------------------------------------------------
__global__ __launch_bounds__(256) void out_proj_kernel(
    const __bf16* __restrict__ z, const __bf16* __restrict__ Wob,
    const float* __restrict__ bout, float* __restrict__ out) {
  __shared__ float red[3][64][33];
  const int tid  = threadIdx.x;
  const int wave = tid >> 6, lane = tid & 63;
  const int l31  = lane & 31, lhi = lane >> 5;
  const int row0 = blockIdx.x * 32;

  const __bf16* zr = z + (size_t)(row0 + l31) * HD + wave * 128 + lhi * 8;

  f32_16 C0, C1;
#pragma unroll
  for (int i = 0; i < 16; i++) { C0[i] = 0.f; C1[i] = 0.f; }

#pragma unroll
  for (int s = 0; s < 8; s++) {
    const int sa = wave * 8 + s;
    bf16_8 a  = *(const bf16_8*)(zr + s * 16);
    bf16_8 b0 = *(const bf16_8*)(Wob + ((size_t)((0 * 32 + sa) * 64 + lane)) * 8);
    bf16_8 b1 = *(const bf16_8*)(Wob + ((size_t)((1 * 32 + sa) * 64 + lane)) * 8);
    C0 = __builtin_amdgcn_mfma_f32_32x32x16_bf16(a, b0, C0, 0, 0, 0);
    C1 = __builtin_amdgcn_mfma_f32_32x32x16_bf16(a, b1, C1, 0, 0, 0);
  }

  if (wave) {
    float* rw = &red[wave - 1][lane][0];
#pragma unroll
    for (int r = 0; r < 16; r++) { rw[r] = C0[r]; rw[16 + r] = C1[r]; }
  }
  __syncthreads();
  if (wave == 0) {
    const float bi0 = bout[l31], bi1 = bout[32 + l31];
#pragma unroll
    for (int r = 0; r < 16; r++) {
      int n = row0 + (r & 3) + 8 * (r >> 2) + 4 * lhi;
      float v0 = C0[r] + red[0][lane][r]      + red[1][lane][r]      + red[2][lane][r];
      float v1 = C1[r] + red[0][lane][16 + r] + red[1][lane][16 + r] + red[2][lane][16 + r];
      out[(size_t)n * 64 + l31]      = v0 + bi0;
      out[(size_t)n * 64 + 32 + l31] = v1 + bi1;
    }
  }
}

// ---------------------------------------------------------------------------
extern "C" void kernel_launch(void* const* d_in, const int* in_sizes, int n_in,
                              void* d_out, int out_size, void* d_ws, size_t ws_size,
                              hipStream_t stream) {
  const float* x    = (const float*)d_in[0];
  const float* Wqkv = (const float*)d_in[1];
  const float* Wout = (const float*)d_in[2];
  const float* bout = (const float*)d_in[3];
  float* out = (float*)d_out;

  const size_t buf_elems = (size_t)BB * HH * NN * DD;  // 8388608
  __bf16* Qw  = (__bf16*)d_ws;
  __bf16* Kw  = Qw  + buf_elems;
  __bf16* Vtw = Kw  + buf_elems;
  __bf16* zw  = Vtw + buf_elems;
  __bf16* Wob = zw  + buf_elems;       // 32768 bf16

  qkv_kernel<<<dim3(24, 65), 512, 0, stream>>>(x, Wqkv, Wout, Qw, Kw, Vtw, Wob);
  attn_kernel<<<BH * (NN / 512), 512, 0, stream>>>(Qw, Kw, Vtw, zw);
  out_proj_kernel<<<NROWS / 32, 256, 0, stream>>>(zw, Wob, bout, out);
}

// Round 16
// 167.138 us; speedup vs baseline: 1.3649x; 1.0097x over previous
//
#include <hip/hip_runtime.h>
#include <math.h>

// Problem constants: B=8, N=2048, DIM=64, H=8
#define BB 8
#define NN 2048
#define DD 64
#define HH 8
#define BH (BB*HH)       // 64
#define HD (HH*DD)       // 512
#define NROWS (BB*NN)    // 16384
#define QKV_COLS (3*HD)  // 1536

typedef __bf16 bf16_8 __attribute__((ext_vector_type(8)));
typedef __bf16 bf16_4 __attribute__((ext_vector_type(4)));
typedef float  f32_16 __attribute__((ext_vector_type(16)));
typedef float  f32_4  __attribute__((ext_vector_type(4)));
typedef int    i32_2  __attribute__((ext_vector_type(2)));

#define QSCALE 0.180336880111f   // 0.125 * log2(e), folded into Q

__device__ __forceinline__ unsigned pack_bf16(float a, float b) {
  union { __bf16 h[2]; unsigned u; } t;
  t.h[0] = (__bf16)a; t.h[1] = (__bf16)b;
  return t.u;
}

__device__ __forceinline__ float fast_exp2(float x) {
#if __has_builtin(__builtin_amdgcn_exp2f)
  return __builtin_amdgcn_exp2f(x);      // raw v_exp_f32
#else
  return __expf(x * 0.69314718056f);
#endif
}

// half-swap across the lane-32 boundary: C-layout row-spread -> A/B-operand
// k-spread (verified rounds 3-15)
__device__ __forceinline__ bf16_8 half_swap(unsigned a0, unsigned a1,
                                            unsigned a2, unsigned a3,
                                            int lhi, int xl) {
  union { unsigned u[4]; bf16_8 v; } F;
#if __has_builtin(__builtin_amdgcn_permlane32_swap)
  i32_2 r02 = __builtin_amdgcn_permlane32_swap((int)a0, (int)a2, false, false);
  i32_2 r13 = __builtin_amdgcn_permlane32_swap((int)a1, (int)a3, false, false);
  F.u[0] = (unsigned)r02.x; F.u[2] = (unsigned)r02.y;
  F.u[1] = (unsigned)r13.x; F.u[3] = (unsigned)r13.y;
#else
  unsigned w0 = (unsigned)__shfl((int)a0, xl, 64);
  unsigned w1 = (unsigned)__shfl((int)a1, xl, 64);
  unsigned w2 = (unsigned)__shfl((int)a2, xl, 64);
  unsigned w3 = (unsigned)__shfl((int)a3, xl, 64);
  F.u[0] = lhi ? w2 : a0;
  F.u[1] = lhi ? w3 : a1;
  F.u[2] = lhi ? a2 : w0;
  F.u[3] = lhi ? a3 : w1;
#endif
  return F.v;
}

// ---------------------------------------------------------------------------
// Kernel 1: QKV projection (r15 math), XCD-SWIZZLED grid: blockIdx.x = row-
// tile (x-dim padded to 72 so g%8 = rt%8), blockIdx.y = col-group. All 24
// col-group blocks sharing one x row-tile land on the SAME XCD -> x rows hit
// that XCD's L2 instead of being re-fetched on 8 XCDs.
// blockIdx.x==64 -> Wob prep; 65..71 -> no-op.
// ---------------------------------------------------------------------------
__global__ __launch_bounds__(512) void qkv_kernel(
    const float* __restrict__ x, const float* __restrict__ Wqkv,
    const float* __restrict__ Wout,
    __bf16* __restrict__ Q, __bf16* __restrict__ K, __bf16* __restrict__ Vt,
    __bf16* __restrict__ Wob) {
  __shared__ __bf16 Wl[64 * 68];        // [col][k], pitch 68
  __shared__ __bf16 T[8][64][34];       // per-wave V-transpose tiles

  const int tid = threadIdx.x;
  const int rt  = blockIdx.x;           // 0..63 work, 64 prep, 65..71 idle

  if (rt >= 64) {
    if (rt == 64) {                     // Wob prep (24 blocks x 512 thr)
      for (int e = blockIdx.y * 512 + tid; e < 512 * 64; e += 24 * 512) {
        int kf = e >> 6, col = e & 63;
        int s = kf >> 4, lh = (kf >> 3) & 1, j = kf & 7;
        int t = col >> 5, lc = col & 31;
        Wob[((size_t)((t * 32 + s) * 64 + lh * 32 + lc)) * 8 + j] = (__bf16)Wout[e];
      }
    }
    return;
  }

  const int wave = tid >> 6;
  const int lane = tid & 63;
  const int l31  = lane & 31, lhi = lane >> 5;
  const int cg    = blockIdx.y;         // 0..23 (64-col group)
  const int col0  = cg * 64;
  const int which = col0 >> 9;          // 0=Q 1=K 2=V
  const float wscl = (which == 0) ? QSCALE : 1.0f;

  // ---- stage W panel: thread t covers col=t&63, k in [8*(t>>6), +8) ----
  {
    const int c  = tid & 63;
    const int k0 = (tid >> 6) * 8;
    bf16_8 w;
#pragma unroll
    for (int j = 0; j < 8; j++) {
      w[j] = (__bf16)(Wqkv[(size_t)(k0 + j) * QKV_COLS + col0 + c] * wscl);
    }
    *(bf16_8*)(&Wl[c * 68 + k0]) = w;   // once per block
  }
  __syncthreads();

  const int row0 = rt * 256 + wave * 32;
  const int b    = row0 >> 11;
  const int n0l  = row0 & 2047;

  // A-frags: A[m=l31][k = s*16 + lhi*8 + j], fp32 -> bf16
  const float* xr = x + (size_t)(row0 + l31) * 64 + lhi * 8;
  bf16_8 af[4];
#pragma unroll
  for (int s = 0; s < 4; s++) {
    f32_4 a0 = *(const f32_4*)(xr + s * 16);
    f32_4 a1 = *(const f32_4*)(xr + s * 16 + 4);
#pragma unroll
    for (int j = 0; j < 4; j++) { af[s][j] = (__bf16)a0[j]; af[s][4 + j] = (__bf16)a1[j]; }
  }

  f32_16 C0, C1;
#pragma unroll
  for (int i = 0; i < 16; i++) { C0[i] = 0.f; C1[i] = 0.f; }

  // B-frags: 8 ds_read_b128 per wave (lane n=col, k along register)
#pragma unroll
  for (int s = 0; s < 4; s++) {
    bf16_8 b0 = *(const bf16_8*)(&Wl[l31 * 68 + s * 16 + lhi * 8]);
    bf16_8 b1 = *(const bf16_8*)(&Wl[(32 + l31) * 68 + s * 16 + lhi * 8]);
    C0 = __builtin_amdgcn_mfma_f32_32x32x16_bf16(af[s], b0, C0, 0, 0, 0);
    C1 = __builtin_amdgcn_mfma_f32_32x32x16_bf16(af[s], b1, C1, 0, 0, 0);
  }

  const int h = cg & 7;

  if (which < 2) {
    __bf16* dst = (which == 0) ? Q : K;
#pragma unroll
    for (int r = 0; r < 16; r++) {
      int nl = (r & 3) + 8 * (r >> 2) + 4 * lhi;
      size_t base = (((size_t)(b * HH + h) * NN) + n0l + nl) * DD;
      dst[base + l31]      = (__bf16)C0[r];
      dst[base + 32 + l31] = (__bf16)C1[r];
    }
  } else {
    // transpose 32n x 64d -> Vt[bh][d][n]  (wave-private tile, no barrier)
    __bf16 (*Tw)[34] = T[wave];
#pragma unroll
    for (int r = 0; r < 16; r++) {
      int nl = (r & 3) + 8 * (r >> 2) + 4 * lhi;
      Tw[l31][nl]      = (__bf16)C0[r];
      Tw[32 + l31][nl] = (__bf16)C1[r];
    }
    __bf16* dst = Vt + (((size_t)(b * HH + h) * DD) + lane) * NN + n0l;
#pragma unroll
    for (int j = 0; j < 4; j++) {
      *(bf16_8*)(dst + j * 8) = *(const bf16_8*)(&Tw[lane][j * 8]);
    }
  }
}

// ---------------------------------------------------------------------------
// Kernel 2: flash attention — r10/r15 core VERBATIM except XCD swizzle:
// bh = (g&7)*8 + ((g>>3)&7), qt = g>>6. The 4 q-tile blocks sharing one bh
// get identical g%8 -> same XCD -> K/V fetched once per bh into that XCD's
// L2 (FETCH 73.8 MB -> ~52 MB predicted).
// ---------------------------------------------------------------------------
#define TILE_ELEMS (128 * 72 + 64 * 136)   // 17920 bf16 = 35840 B per buffer
__global__ __launch_bounds__(512, 2) void attn_kernel(
    const __bf16* __restrict__ Q, const __bf16* __restrict__ K,
    const __bf16* __restrict__ Vt, __bf16* __restrict__ z) {
  __shared__ __bf16 SMEM[2][TILE_ELEMS];   // 71680 B

  const int tid  = threadIdx.x;
  const int wave = tid >> 6;
  const int lane = tid & 63;
  const int l31  = lane & 31;
  const int lhi  = lane >> 5;
  const int xl   = lane ^ 32;
  const int g    = blockIdx.x;
  const int bh   = (g & 7) * 8 + ((g >> 3) & 7);        // same-bh -> same g%8
  const int q0   = (g >> 6) * 512 + wave * 64;          // 64 queries/wave

  const __bf16* Qbase = Q + ((size_t)bh * NN + q0 + l31) * DD + lhi * 8;
  bf16_8 qfa[4], qfb[4];
#pragma unroll
  for (int s = 0; s < 4; s++) {
    qfa[s] = *(const bf16_8*)(Qbase + s * 16);
    qfb[s] = *(const bf16_8*)(Qbase + (size_t)32 * DD + s * 16);
  }

  f32_16 O0a, O1a, O0b, O1b;
#pragma unroll
  for (int i = 0; i < 16; i++) { O0a[i] = 0.f; O1a[i] = 0.f; O0b[i] = 0.f; O1b[i] = 0.f; }
  float lsa = 0.f, lsb = 0.f;

  const __bf16* Kb = K  + (size_t)bh * NN * DD;
  const __bf16* Vb = Vt + (size_t)bh * DD * NN;

  const int krow = tid >> 3, kcol = (tid & 7) * 8;    // K: 128 x 64
  const int vrow = tid >> 4, vcol = (tid & 15) * 8;   // V: 64 x 128
  const __bf16* kgl = Kb + (size_t)krow * 64 + kcol;
  const __bf16* vgl = Vb + (size_t)vrow * NN + vcol;
  const int koff0 = krow * 72 + kcol;
  const int voff0 = 128 * 72 + vrow * 136 + vcol;

  bf16_8 gk[2], gv[2];
#pragma unroll
  for (int i = 0; i < 2; i++) {
    gk[i] = *(const bf16_8*)(kgl + (size_t)i * 64 * 64);
    gv[i] = *(const bf16_8*)(vgl + (size_t)i * 32 * NN);
  }
  {
    __bf16* S = SMEM[0];
    *(bf16_8*)(S + koff0)            = gk[0];
    *(bf16_8*)(S + koff0 + 64 * 72)  = gk[1];
    *(bf16_8*)(S + voff0)            = gv[0];
    *(bf16_8*)(S + voff0 + 32 * 136) = gv[1];
  }
#pragma unroll
  for (int i = 0; i < 2; i++) {
    gk[i] = *(const bf16_8*)(kgl + (size_t)128 * 64 + (size_t)i * 64 * 64);
    gv[i] = *(const bf16_8*)(vgl + 128 + (size_t)i * 32 * NN);
  }
  __syncthreads();

  for (int it = 0; it < 16; it++) {
    __bf16* Ks = SMEM[it & 1];
    __bf16* Vs = SMEM[it & 1] + 128 * 72;

    if (it < 15) {
      __bf16* Sn = SMEM[(it + 1) & 1];
      *(bf16_8*)(Sn + koff0)            = gk[0];
      *(bf16_8*)(Sn + koff0 + 64 * 72)  = gk[1];
      *(bf16_8*)(Sn + voff0)            = gv[0];
      *(bf16_8*)(Sn + voff0 + 32 * 136) = gv[1];
      if (it < 14) {
        const size_t kadv = (size_t)(it + 2) * 128 * 64;
        const size_t vadv = (size_t)(it + 2) * 128;
#pragma unroll
        for (int i = 0; i < 2; i++) {
          gk[i] = *(const bf16_8*)(kgl + kadv + (size_t)i * 64 * 64);
          gv[i] = *(const bf16_8*)(vgl + vadv + (size_t)i * 32 * NN);
        }
      }
    }

#pragma unroll
    for (int grp = 0; grp < 4; grp++) {
      const int kb0 = grp * 32;

      f32_16 Sa, Sb;
#pragma unroll
      for (int i = 0; i < 16; i++) { Sa[i] = 0.f; Sb[i] = 0.f; }
#pragma unroll
      for (int s = 0; s < 4; s++) {
        bf16_8 kb = *(const bf16_8*)(&Ks[(kb0 + l31) * 72 + s * 16 + lhi * 8]);
        Sa = __builtin_amdgcn_mfma_f32_32x32x16_bf16(kb, qfa[s], Sa, 0, 0, 0);
        Sb = __builtin_amdgcn_mfma_f32_32x32x16_bf16(kb, qfb[s], Sb, 0, 0, 0);
      }

      unsigned pka[8], pkb[8];
#pragma unroll
      for (int t = 0; t < 8; t++) {
        float a0 = fast_exp2(Sa[2 * t]), a1 = fast_exp2(Sa[2 * t + 1]);
        lsa += a0 + a1;
        pka[t] = pack_bf16(a0, a1);
        float b0 = fast_exp2(Sb[2 * t]), b1 = fast_exp2(Sb[2 * t + 1]);
        lsb += b0 + b1;
        pkb[t] = pack_bf16(b0, b1);
      }

#pragma unroll
      for (int gq = 0; gq < 2; gq++) {
        const int kc = kb0 + gq * 16;
        bf16_8 va0 = *(const bf16_8*)(&Vs[l31 * 136 + kc + lhi * 8]);
        bf16_8 va1 = *(const bf16_8*)(&Vs[(32 + l31) * 136 + kc + lhi * 8]);
        bf16_8 Fa = half_swap(pka[gq * 4], pka[gq * 4 + 1], pka[gq * 4 + 2], pka[gq * 4 + 3], lhi, xl);
        O0a = __builtin_amdgcn_mfma_f32_32x32x16_bf16(va0, Fa, O0a, 0, 0, 0);
        O1a = __builtin_amdgcn_mfma_f32_32x32x16_bf16(va1, Fa, O1a, 0, 0, 0);
        bf16_8 Fb = half_swap(pkb[gq * 4], pkb[gq * 4 + 1], pkb[gq * 4 + 2], pkb[gq * 4 + 3], lhi, xl);
        O0b = __builtin_amdgcn_mfma_f32_32x32x16_bf16(va0, Fb, O0b, 0, 0, 0);
        O1b = __builtin_amdgcn_mfma_f32_32x32x16_bf16(va1, Fb, O1b, 0, 0, 0);
      }
    }
    __syncthreads();
  }

  lsa += __shfl_xor(lsa, 32, 64);
  lsb += __shfl_xor(lsb, 32, 64);
  const float inva = 1.f / lsa;
  const float invb = 1.f / lsb;

  const int b = bh >> 3, h = bh & 7;
  __bf16* ow = SMEM[0] + wave * (32 * 68);
  const int qr = lane >> 1, c0 = (lane & 1) * 32;
#pragma unroll
  for (int sub = 0; sub < 2; sub++) {
    const f32_16& P0 = sub ? O0b : O0a;
    const f32_16& P1 = sub ? O1b : O1a;
    const float inv = sub ? invb : inva;
#pragma unroll
    for (int gq = 0; gq < 4; gq++) {
      bf16_4 p0, p1;
#pragma unroll
      for (int i = 0; i < 4; i++) {
        p0[i] = (__bf16)(P0[4 * gq + i] * inv);
        p1[i] = (__bf16)(P1[4 * gq + i] * inv);
      }
      const int d0 = 8 * gq + 4 * lhi;
      *(bf16_4*)(ow + l31 * 68 + d0)      = p0;
      *(bf16_4*)(ow + l31 * 68 + 32 + d0) = p1;
    }
    __bf16* zp = z + ((size_t)b * NN + q0 + sub * 32 + qr) * HD + h * DD + c0;
#pragma unroll
    for (int j = 0; j < 4; j++) {
      *(bf16_8*)(zp + 8 * j) = *(const bf16_8*)(ow + qr * 68 + c0 + 8 * j);
    }
  }
}

// ---------------------------------------------------------------------------
// Kernel 3: out projection, k-split x4 (r10-verbatim).
// ---------------------------------------------------------------------------
__global__ __launch_bounds__(256) void out_proj_kernel(
    const __bf16* __restrict__ z, const __bf16* __restrict__ Wob,
    const float* __restrict__ bout, float* __restrict__ out) {
  __shared__ float red[3][64][33];
  const int tid  = threadIdx.x;
  const int wave = tid >> 6, lane = tid & 63;
  const int l31  = lane & 31, lhi = lane >> 5;
  const int row0 = blockIdx.x * 32;

  const __bf16* zr = z + (size_t)(row0 + l31) * HD + wave * 128 + lhi * 8;

  f32_16 C0, C1;
#pragma unroll
  for (int i = 0; i < 16; i++) { C0[i] = 0.f; C1[i] = 0.f; }

#pragma unroll
  for (int s = 0; s < 8; s++) {
    const int sa = wave * 8 + s;
    bf16_8 a  = *(const bf16_8*)(zr + s * 16);
    bf16_8 b0 = *(const bf16_8*)(Wob + ((size_t)((0 * 32 + sa) * 64 + lane)) * 8);
    bf16_8 b1 = *(const bf16_8*)(Wob + ((size_t)((1 * 32 + sa) * 64 + lane)) * 8);
    C0 = __builtin_amdgcn_mfma_f32_32x32x16_bf16(a, b0, C0, 0, 0, 0);
    C1 = __builtin_amdgcn_mfma_f32_32x32x16_bf16(a, b1, C1, 0, 0, 0);
  }

  if (wave) {
    float* rw = &red[wave - 1][lane][0];
#pragma unroll
    for (int r = 0; r < 16; r++) { rw[r] = C0[r]; rw[16 + r] = C1[r]; }
  }
  __syncthreads();
  if (wave == 0) {
    const float bi0 = bout[l31], bi1 = bout[32 + l31];
#pragma unroll
    for (int r = 0; r < 16; r++) {
      int n = row0 + (r & 3) + 8 * (r >> 2) + 4 * lhi;
      float v0 = C0[r] + red[0][lane][r]      + red[1][lane][r]      + red[2][lane][r];
      float v1 = C1[r] + red[0][lane][16 + r] + red[1][lane][16 + r] + red[2][lane][16 + r];
      out[(size_t)n * 64 + l31]      = v0 + bi0;
      out[(size_t)n * 64 + 32 + l31] = v1 + bi1;
    }
  }
}

// ---------------------------------------------------------------------------
extern "C" void kernel_launch(void* const* d_in, const int* in_sizes, int n_in,
                              void* d_out, int out_size, void* d_ws, size_t ws_size,
                              hipStream_t stream) {
  const float* x    = (const float*)d_in[0];
  const float* Wqkv = (const float*)d_in[1];
  const float* Wout = (const float*)d_in[2];
  const float* bout = (const float*)d_in[3];
  float* out = (float*)d_out;

  const size_t buf_elems = (size_t)BB * HH * NN * DD;  // 8388608
  __bf16* Qw  = (__bf16*)d_ws;
  __bf16* Kw  = Qw  + buf_elems;
  __bf16* Vtw = Kw  + buf_elems;
  __bf16* zw  = Vtw + buf_elems;
  __bf16* Wob = zw  + buf_elems;       // 32768 bf16

  qkv_kernel<<<dim3(72, 24), 512, 0, stream>>>(x, Wqkv, Wout, Qw, Kw, Vtw, Wob);
  attn_kernel<<<BH * (NN / 512), 512, 0, stream>>>(Qw, Kw, Vtw, zw);
  out_proj_kernel<<<NROWS / 32, 256, 0, stream>>>(zw, Wob, bout, out);
}